// Round 1
// baseline (359.135 us; speedup 1.0000x reference)
//
#include <hip/hip_runtime.h>

// Legendre2: out = P6 @ C^T + beta, P-recurrence over 6 matvecs with T.
// N=524288, D=64, K=64, O=32, DEGREE=6. All f32 (no fp32 MFMA on CDNA4 ->
// vector-ALU compute-bound, ~28 GFLOP).

#define NN     524288
#define DD     64
#define KK     64
#define OO     32
#define NMAT   6

#define BLOCK  1024
#define GRID   256
#define ROWS_PER_BLOCK (NN / GRID)          // 2048
#define ROWS_PER_PASS  64
#define NPASS  (ROWS_PER_BLOCK / ROWS_PER_PASS)  // 32

// LDS carve (float offsets)
#define A_OFF  0                       // [6][64][64] swizzled A  (24576 f)
#define Z_OFF  24576                   // [64][64] z tile          (4096 f)
#define C_OFF  (24576 + 4096)          // [32][64] swizzled C      (2048 f)
#define P_OFF  (24576 + 4096 + 2048)   // [64][64] p6 tile         (4096 f)
#define SMEM_FLOATS (P_OFF + 4096)     // 34816 floats = 139264 B
#define SMEM_BYTES  (SMEM_FLOATS * 4)

__global__ __launch_bounds__(BLOCK) void legendre2_kernel(
    const float* __restrict__ z, const float* __restrict__ T,
    const float* __restrict__ C, const float* __restrict__ beta,
    float* __restrict__ out)
{
    extern __shared__ float smem[];
    float* A_s = smem + A_OFF;   // A[j][k][d] with d-float4-groups XOR-swizzled by (k&15)
    float* z_s = smem + Z_OFF;   // plain row-major (read as wave-uniform broadcast)
    float* C_s = smem + C_OFF;   // C[o][k] with k-float4-groups XOR-swizzled by (o&15)
    float* p_s = smem + P_OFF;   // plain row-major

    const int tid = (int)threadIdx.x;
    const int k   = tid & 63;
    const int g   = tid >> 6;          // 0..15 row-group

    // ---------------- one-time staging: A (normalize+scale+swizzle) and C ----
    if (tid < NMAT * KK) {
        const int j  = tid >> 6;       // matrix 0..5
        const int kr = tid & 63;       // k-row
        const float* src = T + (size_t)(j * KK + kr) * DD;
        float row[DD];
        float ssum = 0.f;
        #pragma unroll
        for (int d = 0; d < DD; ++d) { row[d] = src[d]; ssum += row[d]; }
        float scale;
        if (j == 0) {
            scale = 1.f;                               // T1: raw, coef=1
        } else {
            const float fi = (float)(j + 1);           // i = j+1 in 2..6
            scale = ((2.f * fi - 1.f) / fi) / ssum;    // coef / rowsum
        }
        float* dst = A_s + (size_t)(j * KK + kr) * DD;
        #pragma unroll
        for (int d4 = 0; d4 < 16; ++d4) {
            const int p4 = d4 ^ (kr & 15);             // bank-spread swizzle
            #pragma unroll
            for (int c = 0; c < 4; ++c) dst[p4 * 4 + c] = scale * row[d4 * 4 + c];
        }
    } else if (tid >= 512) {                            // 512..1023 -> C float4 groups
        const int t2 = tid - 512;                       // 0..511
        const int o  = t2 >> 4;                         // 0..31
        const int k4 = t2 & 15;
        const int p4 = k4 ^ (o & 15);
        #pragma unroll
        for (int c = 0; c < 4; ++c)
            C_s[o * KK + p4 * 4 + c] = C[o * KK + k4 * 4 + c];
    }

    const size_t row0_blk = (size_t)blockIdx.x * ROWS_PER_BLOCK;

    // stage z for pass 0 (coalesced float4; LDS write lane-consecutive)
    {
        float4 z0 = *(const float4*)(z + row0_blk * DD + (size_t)tid * 4);
        *(float4*)(z_s + tid * 4) = z0;
    }
    __syncthreads();

    for (int p = 0; p < NPASS; ++p) {
        // issue next-pass z load EARLY (hides HBM latency under the d-loop)
        float4 zn;
        if (p + 1 < NPASS)
            zn = *(const float4*)(z + (row0_blk + (size_t)(p + 1) * ROWS_PER_PASS) * DD
                                  + (size_t)tid * 4);

        // ---------------- main d-loop: 24 accumulators (4 rows x 6 mats) -----
        float acc[4][6];
        #pragma unroll
        for (int j = 0; j < 4; ++j)
            #pragma unroll
            for (int i = 0; i < 6; ++i) acc[j][i] = 0.f;

        const float* zb = z_s + (size_t)(g * 4) * DD;
        #pragma unroll
        for (int d4 = 0; d4 < 16; ++d4) {
            const int ap = (d4 ^ (k & 15)) << 2;       // un-swizzle on read
            float4 a4[6];
            #pragma unroll
            for (int i = 0; i < 6; ++i)
                a4[i] = *(const float4*)(A_s + (size_t)(i * KK + k) * DD + ap);
            #pragma unroll
            for (int j = 0; j < 4; ++j) {
                const float4 z4 = *(const float4*)(zb + j * DD + (d4 << 2)); // broadcast
                #pragma unroll
                for (int i = 0; i < 6; ++i) {
                    acc[j][i] += z4.x * a4[i].x;
                    acc[j][i] += z4.y * a4[i].y;
                    acc[j][i] += z4.z * a4[i].z;
                    acc[j][i] += z4.w * a4[i].w;
                }
            }
        }

        // ---------------- Legendre recurrence (in-register) -> p6 to LDS -----
        #pragma unroll
        for (int j = 0; j < 4; ++j) {
            float pprev = 1.f;
            float pcurr = acc[j][0];
            #pragma unroll
            for (int i2 = 1; i2 < 6; ++i2) {
                const float fi = (float)(i2 + 1);
                const float b  = (fi - 1.f) / fi;
                const float pn = acc[j][i2] * pcurr - b * pprev;
                pprev = pcurr; pcurr = pn;
            }
            p_s[(g * 4 + j) * KK + k] = pcurr;          // lane-consecutive, no conflict
        }
        __syncthreads();

        // ---------------- epilogue: out = p6 @ C^T + beta --------------------
        {
            const int er = tid >> 5;                    // 0..31 (row)
            const int eo = tid & 31;                    // 0..31 (output col)
            float s0 = 0.f, s1 = 0.f;
            #pragma unroll
            for (int k4 = 0; k4 < 16; ++k4) {
                const int cp = (k4 ^ (eo & 15)) << 2;
                const float4 c4 = *(const float4*)(C_s + eo * KK + cp);
                const float4 pa = *(const float4*)(p_s + er * KK + (k4 << 2));
                const float4 pb = *(const float4*)(p_s + (er + 32) * KK + (k4 << 2));
                s0 += pa.x * c4.x; s0 += pa.y * c4.y; s0 += pa.z * c4.z; s0 += pa.w * c4.w;
                s1 += pb.x * c4.x; s1 += pb.y * c4.y; s1 += pb.z * c4.z; s1 += pb.w * c4.w;
            }
            const float bb = beta[eo];
            const size_t rbase = row0_blk + (size_t)p * ROWS_PER_PASS;
            out[(rbase + er) * OO + eo]      = s0 + bb;
            out[(rbase + er + 32) * OO + eo] = s1 + bb;
        }

        // refill z_s for next pass (all prior readers passed the barrier above)
        if (p + 1 < NPASS) *(float4*)(z_s + tid * 4) = zn;
        __syncthreads();
    }
}

extern "C" void kernel_launch(void* const* d_in, const int* in_sizes, int n_in,
                              void* d_out, int out_size, void* d_ws, size_t ws_size,
                              hipStream_t stream) {
    const float* z    = (const float*)d_in[0];
    const float* T    = (const float*)d_in[1];
    const float* C    = (const float*)d_in[2];
    const float* beta = (const float*)d_in[3];
    float* out = (float*)d_out;

    (void)d_ws; (void)ws_size; (void)in_sizes; (void)n_in; (void)out_size;

    // >64 KiB dynamic LDS opt-in (gfx950: 160 KiB/CU)
    hipFuncSetAttribute((const void*)legendre2_kernel,
                        hipFuncAttributeMaxDynamicSharedMemorySize, SMEM_BYTES);

    legendre2_kernel<<<GRID, BLOCK, SMEM_BYTES, stream>>>(z, T, C, beta, out);
}

// Round 2
// 91.111 us; speedup vs baseline: 3.9417x; 3.9417x over previous
//
#include <hip/hip_runtime.h>

// Legendre2 via split-precision MFMA.
// W_i = Z @ (coef_i * Tnorm_i)^T  done as f16 hi/lo 3-term MFMA (f32 accum),
// elementwise Legendre fold in f32 registers, epilogue P6 @ C^T + beta as
// bf16 hi/lo 3-term MFMA (P6 range ~1e8 requires bf16, not f16).
// N=524288, D=64, K=64, O=32, DEGREE=6.

typedef _Float16 f16x8 __attribute__((ext_vector_type(8)));
typedef short    s16x8 __attribute__((ext_vector_type(8)));
typedef float    f32x4 __attribute__((ext_vector_type(4)));

#define NN      524288
#define BLOCKS  256
#define THREADS 512
#define NWAVES  8

// LDS byte offsets
#define BH_OFF    0                      // 48 frags * 1 KB (f16 hi of A)
#define BL_OFF    49152                  // 48 frags * 1 KB (f16 lo of A)
#define CF_OFF    98304                  // 8 frags * 1 KB (bf16 h/l of C)
#define SCALE_OFF 106496                 // 384 f32 scales
#define SCR_OFF   108032                 // 8 waves * 4 KB transpose scratch
#define SMEM_BYTES (SCR_OFF + NWAVES * 4096)   // 140800 B

__device__ __forceinline__ unsigned short f2bf(float x) {
    unsigned u = __builtin_bit_cast(unsigned, x);
    return (unsigned short)((u + 0x7FFFu + ((u >> 16) & 1u)) >> 16);
}

__global__ __launch_bounds__(THREADS) void leg_mfma(
    const float* __restrict__ z, const float* __restrict__ T,
    const float* __restrict__ Cm, const float* __restrict__ beta,
    float* __restrict__ out)
{
    extern __shared__ char smem[];
    float* scale_s = (float*)(smem + SCALE_OFF);
    const int tid  = (int)threadIdx.x;
    const int lane = tid & 63;
    const int wv   = tid >> 6;
    const int lrow = lane & 15;          // row (A-op) / col (C/D) index
    const int lhi  = lane >> 4;          // 0..3

    // ---------- phase A: per-row scales: j==0 -> 1, else coef_j / rowsum ----
    if (tid < 384) {
        const int mat = tid >> 6, kc = tid & 63;
        const float4* tr = (const float4*)(T + (size_t)((mat << 6) + kc) * 64);
        float s = 0.f;
        #pragma unroll
        for (int q = 0; q < 16; ++q) { float4 v = tr[q]; s += v.x + v.y + v.z + v.w; }
        float sc;
        if (mat == 0) sc = 1.f;
        else { const float fi = (float)(mat + 1); sc = (2.f * fi - 1.f) / fi / s; }
        scale_s[tid] = sc;
    }
    __syncthreads();

    // ---------- phase B: build B-operand frags of A (f16 hi/lo) -------------
    // frag(mat,s,f): lane l supplies B[k=(l>>4)*8+j][col=(l&15)+16f] of the
    // d-range 32s..32s+31, i.e. A[col][32s+(l>>4)*8+j] * scale.
    for (int g = tid; g < 3072; g += THREADS) {
        const int mat = g >> 9;
        const int s   = (g >> 8) & 1;
        const int f   = (g >> 6) & 3;
        const int l   = g & 63;
        const int kc  = (l & 15) + (f << 4);
        const int d0  = ((l >> 4) << 3) + (s << 5);
        const float sc = scale_s[(mat << 6) + kc];
        const float* src = T + (size_t)((mat << 6) + kc) * 64 + d0;
        const float4 v0 = *(const float4*)(src);
        const float4 v1 = *(const float4*)(src + 4);
        const float vv[8] = {v0.x, v0.y, v0.z, v0.w, v1.x, v1.y, v1.z, v1.w};
        f16x8 hi, lo;
        #pragma unroll
        for (int j = 0; j < 8; ++j) {
            const float x = vv[j] * sc;
            const _Float16 h = (_Float16)x;
            hi[j] = h;
            lo[j] = (_Float16)(x - (float)h);
        }
        const int fr = (((mat << 1) + s) << 2) + f;
        *(f16x8*)(smem + BH_OFF + fr * 1024 + l * 16) = hi;
        *(f16x8*)(smem + BL_OFF + fr * 1024 + l * 16) = lo;
    }
    // C-operand frags (bf16 hi/lo): frag(hl,s,fo): lane l supplies
    // C2[k=32s+(l>>4)*8+j][o=(l&15)+16fo] = C[o][k].
    {
        const int hl = (tid >> 8) & 1;
        const int s  = (tid >> 7) & 1;
        const int fo = (tid >> 6) & 1;
        const int l  = tid & 63;
        const int o  = (l & 15) + (fo << 4);
        const int k0 = ((l >> 4) << 3) + (s << 5);
        const float* src = Cm + (size_t)o * 64 + k0;
        const float4 v0 = *(const float4*)src;
        const float4 v1 = *(const float4*)(src + 4);
        const float vv[8] = {v0.x, v0.y, v0.z, v0.w, v1.x, v1.y, v1.z, v1.w};
        s16x8 fr;
        #pragma unroll
        for (int j = 0; j < 8; ++j) {
            const float x = vv[j];
            const unsigned short h = f2bf(x);
            if (hl) {
                const float hf = __builtin_bit_cast(float, (unsigned)h << 16);
                fr[j] = (short)f2bf(x - hf);
            } else {
                fr[j] = (short)h;
            }
        }
        *(s16x8*)(smem + CF_OFF + ((((hl << 1) + s) << 1) + fo) * 1024 + l * 16) = fr;
    }
    __syncthreads();

    // ---------- main: each wave owns 256 rows, 8 iters of 32 rows -----------
    const int    gw      = blockIdx.x * NWAVES + wv;
    const size_t rowbase = (size_t)gw * 256;
    float* scr = (float*)(smem + SCR_OFF + wv * 4096);

    const float beta0 = beta[lrow];
    const float beta1 = beta[16 + lrow];

    // compute W for mat m into acc (fresh, zero-start): 24 MFMA per tile
    f16x8 zh[2][2], zl[2][2];
    auto compute_w = [&](int mat, f32x4 (&acc)[2][4]) {
        #pragma unroll
        for (int f = 0; f < 4; ++f) {
            const int fr0 = mat * 8 + f;       // s=0
            const int fr1 = mat * 8 + 4 + f;   // s=1
            const f16x8 bh0 = *(const f16x8*)(smem + BH_OFF + fr0 * 1024 + lane * 16);
            const f16x8 bl0 = *(const f16x8*)(smem + BL_OFF + fr0 * 1024 + lane * 16);
            const f16x8 bh1 = *(const f16x8*)(smem + BH_OFF + fr1 * 1024 + lane * 16);
            const f16x8 bl1 = *(const f16x8*)(smem + BL_OFF + fr1 * 1024 + lane * 16);
            #pragma unroll
            for (int t = 0; t < 2; ++t) {
                f32x4 a = {0.f, 0.f, 0.f, 0.f};
                a = __builtin_amdgcn_mfma_f32_16x16x32_f16(zh[t][0], bh0, a, 0, 0, 0);
                a = __builtin_amdgcn_mfma_f32_16x16x32_f16(zl[t][0], bh0, a, 0, 0, 0);
                a = __builtin_amdgcn_mfma_f32_16x16x32_f16(zh[t][0], bl0, a, 0, 0, 0);
                a = __builtin_amdgcn_mfma_f32_16x16x32_f16(zh[t][1], bh1, a, 0, 0, 0);
                a = __builtin_amdgcn_mfma_f32_16x16x32_f16(zl[t][1], bh1, a, 0, 0, 0);
                a = __builtin_amdgcn_mfma_f32_16x16x32_f16(zh[t][1], bl1, a, 0, 0, 0);
                acc[t][f] = a;
            }
        }
    };
    // PT = W*PC - b*PT (elementwise on C/D fragments)
    auto fold = [&](float b, f32x4 (&W)[2][4], f32x4 (&PC)[2][4], f32x4 (&PT)[2][4]) {
        #pragma unroll
        for (int t = 0; t < 2; ++t)
            #pragma unroll
            for (int f = 0; f < 4; ++f)
                #pragma unroll
                for (int r = 0; r < 4; ++r)
                    PT[t][f][r] = W[t][f][r] * PC[t][f][r] - b * PT[t][f][r];
    };

    // prologue: load z for iter 0
    float4 zraw[2][4];
    #pragma unroll
    for (int t = 0; t < 2; ++t)
        #pragma unroll
        for (int s = 0; s < 2; ++s) {
            const float* p = z + (rowbase + t * 16 + lrow) * 64 + (s << 5) + (lhi << 3);
            zraw[t][2 * s]     = *(const float4*)(p);
            zraw[t][2 * s + 1] = *(const float4*)(p + 4);
        }

    for (int it = 0; it < 8; ++it) {
        // convert staged z to f16 hi/lo fragments
        #pragma unroll
        for (int t = 0; t < 2; ++t)
            #pragma unroll
            for (int s = 0; s < 2; ++s) {
                const float4 q0 = zraw[t][2 * s], q1 = zraw[t][2 * s + 1];
                const float vv[8] = {q0.x, q0.y, q0.z, q0.w, q1.x, q1.y, q1.z, q1.w};
                #pragma unroll
                for (int j = 0; j < 8; ++j) {
                    const _Float16 h = (_Float16)vv[j];
                    zh[t][s][j] = h;
                    zl[t][s][j] = (_Float16)(vv[j] - (float)h);
                }
            }
        // prefetch next iter's z (in flight across the mat loop)
        if (it < 7) {
            #pragma unroll
            for (int t = 0; t < 2; ++t)
                #pragma unroll
                for (int s = 0; s < 2; ++s) {
                    const float* p = z + (rowbase + (it + 1) * 32 + t * 16 + lrow) * 64
                                       + (s << 5) + (lhi << 3);
                    zraw[t][2 * s]     = *(const float4*)(p);
                    zraw[t][2 * s + 1] = *(const float4*)(p + 4);
                }
        }

        // Legendre chain: pA = P1; pB = P2; ... ping-pong folds; P6 ends in pB
        f32x4 pA[2][4], pB[2][4], wk[2][4];
        compute_w(0, pA);
        compute_w(1, wk);
        #pragma unroll
        for (int t = 0; t < 2; ++t)
            #pragma unroll
            for (int f = 0; f < 4; ++f)
                #pragma unroll
                for (int r = 0; r < 4; ++r)
                    pB[t][f][r] = wk[t][f][r] * pA[t][f][r] - 0.5f;   // pp = ones
        compute_w(2, wk); fold(2.f / 3.f, wk, pB, pA);
        compute_w(3, wk); fold(3.f / 4.f, wk, pA, pB);
        compute_w(4, wk); fold(4.f / 5.f, wk, pB, pA);
        compute_w(5, wk); fold(5.f / 6.f, wk, pA, pB);                // P6 = pB

        // ---------------- epilogue: out = P6 @ C^T + beta -------------------
        // C-frags (shared by both tiles)
        s16x8 ch[2][2], cl[2][2];   // [s][fo]
        #pragma unroll
        for (int s = 0; s < 2; ++s)
            #pragma unroll
            for (int fo = 0; fo < 2; ++fo) {
                ch[s][fo] = *(const s16x8*)(smem + CF_OFF + (((0 + s) << 1) + fo) * 1024 + lane * 16);
                cl[s][fo] = *(const s16x8*)(smem + CF_OFF + ((((2 + s)) << 1) + fo) * 1024 + lane * 16);
            }
        #pragma unroll
        for (int t = 0; t < 2; ++t) {
            // transpose P6 (C/D layout) -> A-op layout via XOR-swizzled scratch
            #pragma unroll
            for (int f = 0; f < 4; ++f)
                #pragma unroll
                for (int r = 0; r < 4; ++r) {
                    const int row = lhi * 4 + r;
                    const int k   = (f << 4) + lrow;
                    const int g4  = (k >> 2) ^ row;            // group swizzle
                    scr[row * 64 + g4 * 4 + (k & 3)] = pB[t][f][r];
                }
            s16x8 p6h[2], p6l[2];
            #pragma unroll
            for (int s = 0; s < 2; ++s) {
                const int g0 = lhi * 2 + s * 8;
                const float4 q0 = *(const float4*)(scr + lrow * 64 + ((g0)     ^ lrow) * 4);
                const float4 q1 = *(const float4*)(scr + lrow * 64 + ((g0 + 1) ^ lrow) * 4);
                const float vv[8] = {q0.x, q0.y, q0.z, q0.w, q1.x, q1.y, q1.z, q1.w};
                #pragma unroll
                for (int j = 0; j < 8; ++j) {
                    const unsigned short h = f2bf(vv[j]);
                    const float hf = __builtin_bit_cast(float, (unsigned)h << 16);
                    p6h[s][j] = (short)h;
                    p6l[s][j] = (short)f2bf(vv[j] - hf);
                }
            }
            #pragma unroll
            for (int fo = 0; fo < 2; ++fo) {
                f32x4 o = {0.f, 0.f, 0.f, 0.f};
                o = __builtin_amdgcn_mfma_f32_16x16x32_bf16(p6h[0], ch[0][fo], o, 0, 0, 0);
                o = __builtin_amdgcn_mfma_f32_16x16x32_bf16(p6l[0], ch[0][fo], o, 0, 0, 0);
                o = __builtin_amdgcn_mfma_f32_16x16x32_bf16(p6h[0], cl[0][fo], o, 0, 0, 0);
                o = __builtin_amdgcn_mfma_f32_16x16x32_bf16(p6h[1], ch[1][fo], o, 0, 0, 0);
                o = __builtin_amdgcn_mfma_f32_16x16x32_bf16(p6l[1], ch[1][fo], o, 0, 0, 0);
                o = __builtin_amdgcn_mfma_f32_16x16x32_bf16(p6h[1], cl[1][fo], o, 0, 0, 0);
                const float bb = fo ? beta1 : beta0;
                const size_t r0 = rowbase + (size_t)it * 32 + t * 16 + lhi * 4;
                #pragma unroll
                for (int r = 0; r < 4; ++r)
                    out[(r0 + r) * 32 + (fo << 4) + lrow] = o[r] + bb;
            }
        }
    }
}

extern "C" void kernel_launch(void* const* d_in, const int* in_sizes, int n_in,
                              void* d_out, int out_size, void* d_ws, size_t ws_size,
                              hipStream_t stream) {
    const float* z    = (const float*)d_in[0];
    const float* T    = (const float*)d_in[1];
    const float* C    = (const float*)d_in[2];
    const float* beta = (const float*)d_in[3];
    float* out = (float*)d_out;
    (void)in_sizes; (void)n_in; (void)out_size; (void)d_ws; (void)ws_size;

    hipFuncSetAttribute((const void*)leg_mfma,
                        hipFuncAttributeMaxDynamicSharedMemorySize, SMEM_BYTES);
    leg_mfma<<<BLOCKS, THREADS, SMEM_BYTES, stream>>>(z, T, C, beta, out);
}